// Round 6
// baseline (114.747 us; speedup 1.0000x reference)
//
#include <hip/hip_runtime.h>
#include <type_traits>
#include <stdint.h>

#define DEV __device__ __forceinline__

typedef float f32x4 __attribute__((ext_vector_type(4)));
typedef short bf16x8 __attribute__((ext_vector_type(8)));
typedef unsigned short u16;
typedef u16 u16x8 __attribute__((ext_vector_type(8)));

static constexpr int BTOT = 65536;
static constexpr int KB   = 64;
static constexpr int NCHT = BTOT / KB;      // 1024 total chunks
static constexpr int NG   = 56;             // true GEMM pairs
static constexpr int NCOLSUM = 45;
static constexpr float INVB = 1.0f / (float)BTOT;

// 64 chunk-windows of 16 chunks. 4 GEMM blocks per window (one per column),
// 512 threads / 8 waves each, ~220 VGPR -> exactly 1 GEMM block per CU
// (owns the CU's LDS pipe). 256 R blocks backfill as GEMM blocks retire.
static constexpr int NWIN   = 64;
static constexpr int NBLK_C = 64;           // blocks per GEMM column
static constexpr int NBLK_R = 256;          // colsum blocks (4 chunks each)
static constexpr int GRID   = 4*NWIN + NBLK_R; // 512

struct Col {
  int nslot, np, nsplit, nb;
  int8_t sexp[10][6];          // slot exps over (s1,y1,s2,y2,x1,x2)
  int8_t pa[16], pb[16];       // pair -> slot indices
  int16_t gout[16];            // pair -> global G slot
  uint8_t ldmask;              // which arrays to load
};

struct Tables {
  int nW, nB, nM, nA, nX;
  int8_t expw[120][7];
  int8_t expb[20][3];
  int8_t expm[56][5];
  int8_t am[35][4];            // 4-var monos (s1,y1,s2,y2), product order
  int8_t xm[10][2];            // 2-var monos, product order
  Col col[4];
  // combine-kernel term tables
  int8_t wtype[120]; int16_t widx[120]; int8_t wpow[120]; // 0:GEMM 1:colA[o] 2:colX[d]
  int8_t mtype[56];  int16_t midx[56];  int8_t mpow[56];  // 0:GEMM 1:colA[o] 2:colA[d]
  int16_t bcol[20];  int8_t bpow[20];
  int err, gcount;
};

constexpr int aidf(const Tables& t,int a,int b,int c,int d){
  for(int i=0;i<t.nA;i++)
    if(t.am[i][0]==a&&t.am[i][1]==b&&t.am[i][2]==c&&t.am[i][3]==d) return i;
  return -1;
}
constexpr int xidf(const Tables& t,int a,int b){
  for(int i=0;i<t.nX;i++) if(t.xm[i][0]==a&&t.xm[i][1]==b) return i;
  return -1;
}

constexpr Tables makeTables(){
  Tables t{};
  t.err = 0;
  // EXP_W (python product order)
  t.nW=0;
  for(int e0=0;e0<4;e0++)for(int e1=0;e1<4;e1++)for(int e2=0;e2<4;e2++)
  for(int e3=0;e3<4;e3++)for(int e4=0;e4<4;e4++)for(int e5=0;e5<4;e5++)
  for(int e6=0;e6<4;e6++) if(e0+e1+e2+e3+e4+e5+e6<=3){
    t.expw[t.nW][0]=(int8_t)e0; t.expw[t.nW][1]=(int8_t)e1; t.expw[t.nW][2]=(int8_t)e2;
    t.expw[t.nW][3]=(int8_t)e3; t.expw[t.nW][4]=(int8_t)e4; t.expw[t.nW][5]=(int8_t)e5;
    t.expw[t.nW][6]=(int8_t)e6; t.nW++;
  }
  t.nB=0;
  for(int e0=0;e0<4;e0++)for(int e1=0;e1<4;e1++)for(int e2=0;e2<4;e2++)
    if(e0+e1+e2<=3){ t.expb[t.nB][0]=(int8_t)e0; t.expb[t.nB][1]=(int8_t)e1; t.expb[t.nB][2]=(int8_t)e2; t.nB++; }
  t.nM=0;
  for(int e0=0;e0<4;e0++)for(int e1=0;e1<4;e1++)for(int e2=0;e2<4;e2++)
  for(int e3=0;e3<4;e3++)for(int e4=0;e4<4;e4++)
    if(e0+e1+e2+e3+e4<=3){
      t.expm[t.nM][0]=(int8_t)e0; t.expm[t.nM][1]=(int8_t)e1; t.expm[t.nM][2]=(int8_t)e2;
      t.expm[t.nM][3]=(int8_t)e3; t.expm[t.nM][4]=(int8_t)e4; t.nM++;
    }
  t.nA=0;
  for(int a=0;a<4;a++)for(int b=0;b<4;b++)for(int c=0;c<4;c++)for(int d=0;d<4;d++)
    if(a+b+c+d<=3){ t.am[t.nA][0]=(int8_t)a; t.am[t.nA][1]=(int8_t)b; t.am[t.nA][2]=(int8_t)c; t.am[t.nA][3]=(int8_t)d; t.nA++; }
  t.nX=0;
  for(int a=0;a<4;a++)for(int b=0;b<4;b++)
    if(a+b<=3){ t.xm[t.nX][0]=(int8_t)a; t.xm[t.nX][1]=(int8_t)b; t.nX++; }

  int wslot[35][10]; int mslot[10][10];
  for(int i=0;i<35;i++)for(int j=0;j<10;j++) wslot[i][j]=-1;
  for(int i=0;i<10;i++)for(int j=0;j<10;j++) mslot[i][j]=-1;

  int slot=0;

  // --- Col 0: M (y-monos of (y1,y2), shared A/B slot set) ---
  {
    Col& c = t.col[0]; c.nslot=5; c.nsplit=1; c.nb=NBLK_C;
    int ye[5][2] = {{0,1},{1,0},{0,2},{1,1},{2,0}};   // (y1e,y2e)
    int xmid[5] = {0,0,0,0,0};
    for(int s=0;s<5;s++){
      c.sexp[s][0]=0; c.sexp[s][1]=(int8_t)ye[s][0]; c.sexp[s][2]=0;
      c.sexp[s][3]=(int8_t)ye[s][1]; c.sexp[s][4]=0; c.sexp[s][5]=0;
      xmid[s]=xidf(t, ye[s][0], ye[s][1]);
      if(xmid[s]<0) t.err+=1;
    }
    int p=0;
    for(int L=0;L<2;L++)for(int R=0;R<5;R++){
      c.pa[p]=(int8_t)L; c.pb[p]=(int8_t)R; c.gout[p]=(int16_t)slot;
      mslot[xmid[L]][xmid[R]]=slot; slot++; p++;
    }
    for(int L=2;L<5;L++)for(int R=0;R<2;R++){
      c.pa[p]=(int8_t)L; c.pb[p]=(int8_t)R; c.gout[p]=(int16_t)slot;
      mslot[xmid[L]][xmid[R]]=slot; slot++; p++;
    }
    c.np=p;
    if(p!=16) t.err+=1;
  }
  // --- Col 1/2: W1 (s1,y1) and W2 (s2,y2) ---
  for(int wc=0; wc<2; wc++){
    Col& c = t.col[1+wc]; c.nslot=10; c.nsplit=1; c.nb=NBLK_C;
    int ae[5][2] = {{1,0},{0,1},{2,0},{1,1},{0,2}};
    int xe[5][2] = {{0,1},{1,0},{0,2},{1,1},{2,0}};
    int amid[5]={0,0,0,0,0}, xmidb[5]={0,0,0,0,0};
    for(int s=0;s<5;s++){
      for(int q=0;q<6;q++) c.sexp[s][q]=0;
      if(wc==0){ c.sexp[s][0]=(int8_t)ae[s][0]; c.sexp[s][1]=(int8_t)ae[s][1];
                 amid[s]=aidf(t, ae[s][0], ae[s][1], 0, 0); }
      else     { c.sexp[s][2]=(int8_t)ae[s][0]; c.sexp[s][3]=(int8_t)ae[s][1];
                 amid[s]=aidf(t, 0, 0, ae[s][0], ae[s][1]); }
      if(amid[s]<0) t.err+=1;
      for(int q=0;q<6;q++) c.sexp[5+s][q]=0;
      c.sexp[5+s][4]=(int8_t)xe[s][0]; c.sexp[5+s][5]=(int8_t)xe[s][1];
      xmidb[s]=xidf(t, xe[s][0], xe[s][1]);
      if(xmidb[s]<0) t.err+=1;
    }
    int p=0;
    for(int a=0;a<2;a++)for(int b=0;b<5;b++){
      c.pa[p]=(int8_t)a; c.pb[p]=(int8_t)(5+b); c.gout[p]=(int16_t)slot;
      wslot[amid[a]][xmidb[b]]=slot; slot++; p++;
    }
    for(int a=2;a<5;a++)for(int b=0;b<2;b++){
      c.pa[p]=(int8_t)a; c.pb[p]=(int8_t)(5+b); c.gout[p]=(int16_t)slot;
      wslot[amid[a]][xmidb[b]]=slot; slot++; p++;
    }
    c.np=p;
    if(p!=16) t.err+=1;
  }
  // --- Col 3: W3 (mixed deg-2 v's x deg-1 u's) ---
  {
    Col& c = t.col[3]; c.nslot=6; c.nsplit=2; c.nb=NBLK_C;
    int ae4[4][4] = {{1,0,1,0},{1,0,0,1},{0,1,1,0},{0,1,0,1}};
    int xe[2][2] = {{0,1},{1,0}};
    int amid[4]={0,0,0,0}, xmidb[2]={0,0};
    for(int s=0;s<4;s++){
      c.sexp[s][0]=(int8_t)ae4[s][0]; c.sexp[s][1]=(int8_t)ae4[s][1];
      c.sexp[s][2]=(int8_t)ae4[s][2]; c.sexp[s][3]=(int8_t)ae4[s][3];
      c.sexp[s][4]=0; c.sexp[s][5]=0;
      amid[s]=aidf(t, ae4[s][0], ae4[s][1], ae4[s][2], ae4[s][3]);
      if(amid[s]<0) t.err+=1;
    }
    for(int s=0;s<2;s++){
      for(int q=0;q<6;q++) c.sexp[4+s][q]=0;
      c.sexp[4+s][4]=(int8_t)xe[s][0]; c.sexp[4+s][5]=(int8_t)xe[s][1];
      xmidb[s]=xidf(t, xe[s][0], xe[s][1]);
      if(xmidb[s]<0) t.err+=1;
    }
    int p=0;
    for(int a=0;a<4;a++)for(int b=0;b<2;b++){
      c.pa[p]=(int8_t)a; c.pb[p]=(int8_t)(4+b); c.gout[p]=(int16_t)slot;
      wslot[amid[a]][xmidb[b]]=slot; slot++; p++;
    }
    c.np=p;
    if(p!=8) t.err+=1;
  }
  t.gcount=slot;
  if(slot!=NG) t.err+=1;

  // ldmask from slot exps
  for(int ci=0; ci<4; ci++){
    unsigned m=0;
    for(int s=0;s<t.col[ci].nslot;s++)
      for(int v=0;v<6;v++) if(t.col[ci].sexp[s][v]>0) m |= (1u<<v);
    t.col[ci].ldmask=(uint8_t)m;
  }

  // --- combine tables ---
  for(int i=0;i<t.nW;i++){
    const int8_t* e=t.expw[i];
    bool u0=(e[0]==0&&e[3]==0);
    bool v0=(e[1]==0&&e[2]==0&&e[4]==0&&e[5]==0);
    t.wpow[i]=e[6];
    if(u0){ t.wtype[i]=1; t.widx[i]=(int16_t)aidf(t,e[1],e[2],e[4],e[5]); }
    else if(v0){ t.wtype[i]=2; t.widx[i]=(int16_t)xidf(t,e[0],e[3]); }
    else {
      int s=wslot[aidf(t,e[1],e[2],e[4],e[5])][xidf(t,e[0],e[3])];
      if(s<0) t.err+=1;
      t.wtype[i]=0; t.widx[i]=(int16_t)s;
    }
  }
  for(int i=0;i<t.nM;i++){
    const int8_t* e=t.expm[i];
    bool L0=(e[1]==0&&e[3]==0), R0=(e[0]==0&&e[2]==0);
    t.mpow[i]=e[4];
    if(L0){ t.mtype[i]=2; t.midx[i]=(int16_t)aidf(t,0,e[0],0,e[2]); }
    else if(R0){ t.mtype[i]=1; t.midx[i]=(int16_t)aidf(t,0,e[1],0,e[3]); }
    else {
      int s=mslot[xidf(t,e[1],e[3])][xidf(t,e[0],e[2])];
      if(s<0) t.err+=1;
      t.mtype[i]=0; t.midx[i]=(int16_t)s;
    }
  }
  for(int i=0;i<t.nB;i++){
    const int8_t* e=t.expb[i];
    t.bcol[i]=(int16_t)aidf(t,0,e[0],0,e[1]); t.bpow[i]=e[2];
  }
  return t;
}

constexpr Tables TB = makeTables();
static_assert(TB.err==0 && TB.gcount==56, "table build failed");
static_assert(TB.nW==120 && TB.nB==20 && TB.nM==56 && TB.nA==35 && TB.nX==10, "enumeration mismatch");

// wave -> (pair1, pair2) grouping. Pairs in a wave share A-slot (or B-slot for
// the w4 oddballs). Cols 0-2: 16 pairs / 8 waves; col 3: 8 pairs / 8 waves.
constexpr int WP1[4][8] = {
  {0,2,5,7,4,10,12,14},
  {0,2,5,7,4,10,12,14},
  {0,2,5,7,4,10,12,14},
  {0,1,2,3,4,5,6,7}
};
constexpr int WP2[4][8] = {
  {1,3,6,8,9,11,13,15},
  {1,3,6,8,9,11,13,15},
  {1,3,6,8,9,11,13,15},
  {-1,-1,-1,-1,-1,-1,-1,-1}
};
constexpr bool wpOK(){
  for(int c=0;c<4;c++){
    bool used[16]={};
    for(int w=0;w<8;w++){
      int p1=WP1[c][w], p2=WP2[c][w];
      if(p1<0||p1>=TB.col[c].np) return false;
      if(used[p1]) return false; used[p1]=true;
      if(p2>=0){
        if(p2>=TB.col[c].np) return false;
        if(used[p2]) return false; used[p2]=true;
        if(TB.col[c].pa[p1]!=TB.col[c].pa[p2] && TB.col[c].pb[p1]!=TB.col[c].pb[p2]) return false;
      }
    }
    for(int p=0;p<TB.col[c].np;p++) if(!used[p]) return false;
  }
  return true;
}
static_assert(wpOK(), "wave pair grouping invalid");

// ---- helpers ----
template<int N, typename F>
DEV void sunroll(F&& f){
  if constexpr (N > 0){
    sunroll<N-1>(static_cast<F&&>(f));
    f(std::integral_constant<int, N-1>{});
  }
}
template<int E> DEV float ipw(float x){
  if constexpr(E==0) return 1.0f;
  else if constexpr(E==1) return x;
  else if constexpr(E==2) return x*x;
  else return x*x*x;
}
DEV u16 f2bf(float f){
  uint32_t u = __builtin_bit_cast(uint32_t, f);
  u = u + 0x7FFFu + ((u>>16)&1u);
  return (u16)(u>>16);
}

// Fragment-major LDS layout (identical values to r5 -> bit-identical G):
// element (b,ch) of a slot at u16 index ((b>>5)*4 + (ch>>4))*64*8
//   + (((b>>3)&3)*16 + (ch&15))*8 + (b&7)
DEV bf16x8 readFrag(const u16* lds, int slot, int sb, int t, int l){
  return *(const bf16x8*)&lds[slot*4096 + ((sb*4 + t)*64 + l)*8];
}

DEV f32x4 mfma_(bf16x8 a, bf16x8 b, f32x4 c){
  return __builtin_amdgcn_mfma_f32_16x16x32_bf16(a, b, c, 0, 0, 0);
}

// ---- GEMM column: 8 waves x 2 pairs (128x64/wave), 1 block per CU ----
template<int CI>
DEV void colGemm(const float* __restrict__ s1,const float* __restrict__ y1,
                 const float* __restrict__ s2,const float* __restrict__ y2,
                 const float* __restrict__ x1,const float* __restrict__ x2,
                 float* __restrict__ G, u16* lds, int tid, int bi)
{
  constexpr int NS = TB.col[CI].nslot;
  constexpr unsigned LM = TB.col[CI].ldmask;

  const int l = tid&63, w = tid>>6;     // 8 waves
  // staging: thread (w,l) owns b = w*8+j (j=0..7), ch = l -> one b128 write/slot
  const int wbase = (((w>>2)*4 + (l>>4))*64 + (w&3)*16 + (l&15))*8;

  const int c0 = bi*16, c1 = c0+16;     // 16 chunks per block
  f32x4 accA[4][4] = {};
  f32x4 accB[4][4] = {};

  float raw[6][8] = {};
  float nraw[6][8] = {};

  auto issue = [&](int ck, float (&dst)[6][8]){
    const int b0 = (ck*KB + w*8)*64 + l;
    #pragma unroll
    for(int j=0;j<8;j++){
      const int off = b0 + j*64;
      if constexpr(LM&1u)  dst[0][j]=s1[off];
      if constexpr(LM&2u)  dst[1][j]=y1[off];
      if constexpr(LM&4u)  dst[2][j]=s2[off];
      if constexpr(LM&8u)  dst[3][j]=y2[off];
      if constexpr(LM&16u) dst[4][j]=x1[off];
      if constexpr(LM&32u) dst[5][j]=x2[off];
    }
  };

  issue(c0, raw);                       // prologue load

  for(int ck=c0; ck<c1; ++ck){
    // prefetch next chunk into regs (in flight across both barriers)
    const int nk = (ck+1<c1)? ck+1 : c0;
    issue(nk, nraw);

    // stage monomials of current chunk (one b128 write per slot per thread)
    sunroll<NS>([&](auto S){
      constexpr int s = decltype(S)::value;
      u16x8 o8;
      #pragma unroll
      for(int j=0;j<8;j++){
        float v = ipw<TB.col[CI].sexp[s][0]>(raw[0][j])
                * ipw<TB.col[CI].sexp[s][1]>(raw[1][j])
                * ipw<TB.col[CI].sexp[s][2]>(raw[2][j])
                * ipw<TB.col[CI].sexp[s][3]>(raw[3][j])
                * ipw<TB.col[CI].sexp[s][4]>(raw[4][j])
                * ipw<TB.col[CI].sexp[s][5]>(raw[5][j]);
        o8[j]=f2bf(v);
      }
      *(u16x8*)&lds[s*4096 + wbase] = o8;
    });

    // barrier 1: ds_writes visible; do NOT drain vmcnt
    asm volatile("s_waitcnt lgkmcnt(0)" ::: "memory");
    __builtin_amdgcn_s_barrier();
    __builtin_amdgcn_sched_barrier(0);

    // MFMA phase: per-wave constexpr config (wave-uniform branch; barrier
    // counts stay uniform since barriers are outside the branch)
    sunroll<8>([&](auto WW){
      constexpr int ww = decltype(WW)::value;
      if(w==ww){
        constexpr int P1 = WP1[CI][ww], P2 = WP2[CI][ww];
        constexpr int SA1 = TB.col[CI].pa[P1], SB1 = TB.col[CI].pb[P1];
        #pragma unroll
        for(int sb=0; sb<2; ++sb){
          if constexpr(P2 >= 0){
            constexpr int SA2 = TB.col[CI].pa[P2], SB2 = TB.col[CI].pb[P2];
            if constexpr(SA1 == SA2){
              bf16x8 Af[4];
              #pragma unroll
              for(int o2=0;o2<4;o2++) Af[o2]=readFrag(lds,SA1,sb,o2,l);
              #pragma unroll
              for(int dd=0;dd<4;dd++){
                bf16x8 Bf1=readFrag(lds,SB1,sb,dd,l);
                #pragma unroll
                for(int o2=0;o2<4;o2++) accA[o2][dd]=mfma_(Af[o2],Bf1,accA[o2][dd]);
                bf16x8 Bf2=readFrag(lds,SB2,sb,dd,l);
                #pragma unroll
                for(int o2=0;o2<4;o2++) accB[o2][dd]=mfma_(Af[o2],Bf2,accB[o2][dd]);
              }
            } else {
              bf16x8 Af1[4], Af2[4];
              #pragma unroll
              for(int o2=0;o2<4;o2++){ Af1[o2]=readFrag(lds,SA1,sb,o2,l); Af2[o2]=readFrag(lds,SA2,sb,o2,l); }
              #pragma unroll
              for(int dd=0;dd<4;dd++){
                bf16x8 Bf=readFrag(lds,SB1,sb,dd,l);
                #pragma unroll
                for(int o2=0;o2<4;o2++) accA[o2][dd]=mfma_(Af1[o2],Bf,accA[o2][dd]);
                #pragma unroll
                for(int o2=0;o2<4;o2++) accB[o2][dd]=mfma_(Af2[o2],Bf,accB[o2][dd]);
              }
            }
          } else {
            bf16x8 Af[4];
            #pragma unroll
            for(int o2=0;o2<4;o2++) Af[o2]=readFrag(lds,SA1,sb,o2,l);
            #pragma unroll
            for(int dd=0;dd<4;dd++){
              bf16x8 Bf=readFrag(lds,SB1,sb,dd,l);
              #pragma unroll
              for(int o2=0;o2<4;o2++) accA[o2][dd]=mfma_(Af[o2],Bf,accA[o2][dd]);
            }
          }
        }
      }
    });

    // barrier 2: reads consumed before next staging overwrites LDS
    __builtin_amdgcn_sched_barrier(0);
    __builtin_amdgcn_s_barrier();
    __builtin_amdgcn_sched_barrier(0);

    #pragma unroll
    for(int a=0;a<6;a++)
      #pragma unroll
      for(int j=0;j<8;j++) raw[a][j]=nraw[a][j];
  }

  // epilogue: atomic-add partials (C/D layout: col=lane&15, row=(lane>>4)*4+reg)
  const int r0=(l>>4)*4, cc=l&15;
  sunroll<8>([&](auto WW){
    constexpr int ww = decltype(WW)::value;
    if(w==ww){
      constexpr int P1 = WP1[CI][ww], P2 = WP2[CI][ww];
      constexpr int G1 = TB.col[CI].gout[P1];
      {
        float* dst = G + G1*4096;
        #pragma unroll
        for(int o2=0;o2<4;o2++)
          #pragma unroll
          for(int dd=0;dd<4;dd++)
            #pragma unroll
            for(int r=0;r<4;r++)
              atomicAdd(&dst[(o2*16+r0+r)*64 + dd*16+cc], accA[o2][dd][r]);
      }
      if constexpr(P2 >= 0){
        constexpr int G2 = TB.col[CI].gout[P2];
        float* dst = G + G2*4096;
        #pragma unroll
        for(int o2=0;o2<4;o2++)
          #pragma unroll
          for(int dd=0;dd<4;dd++)
            #pragma unroll
            for(int r=0;r<4;r++)
              atomicAdd(&dst[(o2*16+r0+r)*64 + dd*16+cc], accB[o2][dd][r]);
      }
    }
  });
}

// ---- reduction block (512 thr): all 45 colsums in fp32, 4 chunks each ----
DEV void colRed(const float* __restrict__ s1,const float* __restrict__ y1,
                const float* __restrict__ s2,const float* __restrict__ y2,
                const float* __restrict__ x1,const float* __restrict__ x2,
                float* __restrict__ col, float* ldsF, int tid, int bi)
{
  const int ch=tid&63, g8=tid>>6;
  const int row0 = bi*256;
  float accv[45];
  sunroll<45>([&](auto K){ accv[decltype(K)::value]=0.f; });
  for(int r=row0+g8; r<row0+256; r+=8){
    const int off=r*64+ch;
    const float v0=s1[off],v1=y1[off],v2=s2[off],v3=y2[off],v4=x1[off],v5=x2[off];
    sunroll<35>([&](auto K){
      constexpr int k=decltype(K)::value;
      accv[k] += ipw<TB.am[k][0]>(v0)*ipw<TB.am[k][1]>(v1)*ipw<TB.am[k][2]>(v2)*ipw<TB.am[k][3]>(v3);
    });
    sunroll<10>([&](auto K){
      constexpr int k=decltype(K)::value;
      accv[35+k] += ipw<TB.xm[k][0]>(v4)*ipw<TB.xm[k][1]>(v5);
    });
  }
  sunroll<6>([&](auto RR){
    constexpr int rr=decltype(RR)::value;
    __syncthreads();
    sunroll<8>([&](auto Q){
      constexpr int q=decltype(Q)::value;
      if constexpr(rr*8+q < 45)
        ldsF[(q*8+g8)*64+ch]=accv[rr*8+q];
    });
    __syncthreads();
    {
      const int k=tid>>6, c=tid&63;
      const int idx=rr*8+k;
      if(idx<45){
        float s=0.f;
        #pragma unroll
        for(int gg=0; gg<8; gg++) s+=ldsF[(k*8+gg)*64+c];
        atomicAdd(&col[idx*64+c], s);
      }
    }
  });
}

__global__ __launch_bounds__(512, 2) void k_main(
    const float* __restrict__ x1, const float* __restrict__ s1, const float* __restrict__ y1,
    const float* __restrict__ x2, const float* __restrict__ s2, const float* __restrict__ y2,
    float* __restrict__ G, float* __restrict__ col)
{
  __shared__ u16 lds[10*4096];   // 80 KiB
  const int tid = threadIdx.x;
  const int bx = blockIdx.x;
  if (bx < 4*NWIN){
    const int u = bx >> 6;       // column
    const int g = bx & 63;       // chunk-window (XCD = g%8 for all 4 columns)
    if      (u==0) colGemm<0>(s1,y1,s2,y2,x1,x2,G,lds,tid,g);
    else if (u==1) colGemm<1>(s1,y1,s2,y2,x1,x2,G,lds,tid,g);
    else if (u==2) colGemm<2>(s1,y1,s2,y2,x1,x2,G,lds,tid,g);
    else           colGemm<3>(s1,y1,s2,y2,x1,x2,G,lds,tid,g);
  } else {
    colRed(s1,y1,s2,y2,x1,x2,col,(float*)lds,tid, bx - 4*NWIN);
  }
}

__global__ __launch_bounds__(256) void k_combine(
    const float* __restrict__ G, const float* __restrict__ col,
    const float* __restrict__ w, const float* __restrict__ b, const float* __restrict__ m,
    const float* __restrict__ parw, const float* __restrict__ parb, const float* __restrict__ parm,
    float* __restrict__ out)
{
  const int n = blockIdx.x*256 + threadIdx.x;   // 0..4095
  const int o = n>>6, d = n&63;
  const float wv = w[n], mv = m[n];
  const float wp[4] = {1.f, wv, wv*wv, wv*wv*wv};
  const float mp[4] = {1.f, mv, mv*mv, mv*mv*mv};
  float aw=0.f, am=0.f;
  sunroll<120>([&](auto II){
    constexpr int i = decltype(II)::value;
    constexpr int ty = TB.wtype[i];
    constexpr int ix = TB.widx[i];
    constexpr int q  = TB.wpow[i];
    float val;
    if constexpr(ty==0) val = G[ix*4096 + n];
    else if constexpr(ty==1) val = col[ix*64 + o];
    else val = col[(35+ix)*64 + d];
    aw += parw[i] * val * wp[q];
  });
  sunroll<56>([&](auto II){
    constexpr int i = decltype(II)::value;
    constexpr int ty = TB.mtype[i];
    constexpr int ix = TB.midx[i];
    constexpr int q  = TB.mpow[i];
    float val;
    if constexpr(ty==0) val = G[ix*4096 + n];
    else if constexpr(ty==1) val = col[ix*64 + o];
    else val = col[ix*64 + d];
    am += parm[i] * val * mp[q];
  });
  aw *= INVB; am *= INVB;
  if (o==d) am += parm[56];
  out[n] = aw;
  out[4160 + n] = am;
  if (n < 64){
    const float bv = b[n];
    const float bp[4] = {1.f, bv, bv*bv, bv*bv*bv};
    float ab=0.f;
    sunroll<20>([&](auto II){
      constexpr int i = decltype(II)::value;
      constexpr int cix = TB.bcol[i];
      constexpr int q = TB.bpow[i];
      ab += parb[i] * col[cix*64 + n] * bp[q];
    });
    out[4096 + n] = ab * INVB;
  }
}

extern "C" void kernel_launch(void* const* d_in, const int* in_sizes, int n_in,
                              void* d_out, int out_size, void* d_ws, size_t ws_size,
                              hipStream_t stream)
{
  const float* x1=(const float*)d_in[0];
  const float* s1=(const float*)d_in[1];
  const float* y1=(const float*)d_in[2];
  const float* x2=(const float*)d_in[3];
  const float* s2=(const float*)d_in[4];
  const float* y2=(const float*)d_in[5];
  const float* w =(const float*)d_in[6];
  const float* b =(const float*)d_in[7];
  const float* m =(const float*)d_in[8];
  const float* parw=(const float*)d_in[9];
  const float* parb=(const float*)d_in[10];
  const float* parm=(const float*)d_in[11];

  float* G   = (float*)d_ws;
  float* col = G + NG*4096;

  hipMemsetAsync(d_ws, 0, (size_t)(NG*4096 + NCOLSUM*64)*sizeof(float), stream);
  k_main<<<GRID, 512, 0, stream>>>(x1,s1,y1,x2,s2,y2,G,col);
  k_combine<<<16, 256, 0, stream>>>(G,col,w,b,m,parw,parb,parm,(float*)d_out);
}

// Round 7
// 97.107 us; speedup vs baseline: 1.1817x; 1.1817x over previous
//
#include <hip/hip_runtime.h>
#include <type_traits>
#include <stdint.h>

#define DEV __device__ __forceinline__

typedef float f32x4 __attribute__((ext_vector_type(4)));
typedef short bf16x8 __attribute__((ext_vector_type(8)));
typedef unsigned short u16;
typedef u16 u16x4 __attribute__((ext_vector_type(4)));

static constexpr int BTOT = 65536;
static constexpr int KB   = 64;
static constexpr int NCHT = BTOT / KB;      // 1024 total chunks
static constexpr int NG   = 56;             // true GEMM pairs
static constexpr int NCOLSUM = 45;
static constexpr float INVB = 1.0f / (float)BTOT;

// 32 chunk-windows of 32 chunks (2048 rows). Per window: 7 GEMM blocks
// (one per column, 8 pairs each) + 1 colsum block. grid = 8 units x 32
// windows = 256 blocks = exactly 1 per CU. bx = u*32+g -> all 8 blocks of
// window g land on XCD g%8; window working set (6 arrays x 512KB = 3MB)
// fits the 4MB XCD L2.
static constexpr int NWIN  = 32;
static constexpr int CHW   = NCHT / NWIN;   // 32 chunks per GEMM block
static constexpr int NCOLG = 7;
static constexpr int GRID  = 8*NWIN;        // 256
static constexpr int BUFHALF = 8*4096;      // u16s per LDS buffer (8 slots)

struct Col {
  int nslot, np;
  int8_t sexp[8][6];           // slot exps over (s1,y1,s2,y2,x1,x2)
  int8_t pa[8], pb[8];         // pair -> slot indices
  int16_t gout[8];             // pair -> global G slot
  uint8_t ldmask;              // which arrays to load
};

struct Tables {
  int nW, nB, nM, nA, nX;
  int8_t expw[120][7];
  int8_t expb[20][3];
  int8_t expm[56][5];
  int8_t am[35][4];            // 4-var monos (s1,y1,s2,y2), product order
  int8_t xm[10][2];            // 2-var monos, product order
  Col col[NCOLG];
  // combine-kernel term tables
  int8_t wtype[120]; int16_t widx[120]; int8_t wpow[120]; // 0:GEMM 1:colA[o] 2:colX[d]
  int8_t mtype[56];  int16_t midx[56];  int8_t mpow[56];  // 0:GEMM 1:colA[o] 2:colA[d]
  int16_t bcol[20];  int8_t bpow[20];
  int err, gcount;
};

constexpr int aidf(const Tables& t,int a,int b,int c,int d){
  for(int i=0;i<t.nA;i++)
    if(t.am[i][0]==a&&t.am[i][1]==b&&t.am[i][2]==c&&t.am[i][3]==d) return i;
  return -1;
}
constexpr int xidf(const Tables& t,int a,int b){
  for(int i=0;i<t.nX;i++) if(t.xm[i][0]==a&&t.xm[i][1]==b) return i;
  return -1;
}

constexpr Tables makeTables(){
  Tables t{};
  t.err = 0;
  // EXP_W (python product order)
  t.nW=0;
  for(int e0=0;e0<4;e0++)for(int e1=0;e1<4;e1++)for(int e2=0;e2<4;e2++)
  for(int e3=0;e3<4;e3++)for(int e4=0;e4<4;e4++)for(int e5=0;e5<4;e5++)
  for(int e6=0;e6<4;e6++) if(e0+e1+e2+e3+e4+e5+e6<=3){
    t.expw[t.nW][0]=(int8_t)e0; t.expw[t.nW][1]=(int8_t)e1; t.expw[t.nW][2]=(int8_t)e2;
    t.expw[t.nW][3]=(int8_t)e3; t.expw[t.nW][4]=(int8_t)e4; t.expw[t.nW][5]=(int8_t)e5;
    t.expw[t.nW][6]=(int8_t)e6; t.nW++;
  }
  t.nB=0;
  for(int e0=0;e0<4;e0++)for(int e1=0;e1<4;e1++)for(int e2=0;e2<4;e2++)
    if(e0+e1+e2<=3){ t.expb[t.nB][0]=(int8_t)e0; t.expb[t.nB][1]=(int8_t)e1; t.expb[t.nB][2]=(int8_t)e2; t.nB++; }
  t.nM=0;
  for(int e0=0;e0<4;e0++)for(int e1=0;e1<4;e1++)for(int e2=0;e2<4;e2++)
  for(int e3=0;e3<4;e3++)for(int e4=0;e4<4;e4++)
    if(e0+e1+e2+e3+e4<=3){
      t.expm[t.nM][0]=(int8_t)e0; t.expm[t.nM][1]=(int8_t)e1; t.expm[t.nM][2]=(int8_t)e2;
      t.expm[t.nM][3]=(int8_t)e3; t.expm[t.nM][4]=(int8_t)e4; t.nM++;
    }
  t.nA=0;
  for(int a=0;a<4;a++)for(int b=0;b<4;b++)for(int c=0;c<4;c++)for(int d=0;d<4;d++)
    if(a+b+c+d<=3){ t.am[t.nA][0]=(int8_t)a; t.am[t.nA][1]=(int8_t)b; t.am[t.nA][2]=(int8_t)c; t.am[t.nA][3]=(int8_t)d; t.nA++; }
  t.nX=0;
  for(int a=0;a<4;a++)for(int b=0;b<4;b++)
    if(a+b<=3){ t.xm[t.nX][0]=(int8_t)a; t.xm[t.nX][1]=(int8_t)b; t.nX++; }

  int wslot[35][10]; int mslot[10][10];
  for(int i=0;i<35;i++)for(int j=0;j<10;j++) wslot[i][j]=-1;
  for(int i=0;i<10;i++)for(int j=0;j<10;j++) mslot[i][j]=-1;

  int slot=0;

  // --- Col 0: M1 = L(deg1) x R in {y2,y1,y2^2,y1y2} ---
  {
    Col& c=t.col[0]; c.nslot=4; c.np=8;
    int ym[4][2]={{0,1},{1,0},{0,2},{1,1}};   // (y1e,y2e)
    for(int s=0;s<4;s++){ for(int q=0;q<6;q++)c.sexp[s][q]=0;
      c.sexp[s][1]=(int8_t)ym[s][0]; c.sexp[s][3]=(int8_t)ym[s][1]; }
    int p=0;
    for(int L=0;L<2;L++)for(int R=0;R<4;R++){
      c.pa[p]=(int8_t)L; c.pb[p]=(int8_t)R; c.gout[p]=(int16_t)slot;
      mslot[xidf(t,ym[L][0],ym[L][1])][xidf(t,ym[R][0],ym[R][1])]=slot; slot++; p++;
    }
  }
  // --- Col 1: M2 = L(deg1) x y1^2  +  L(deg2) x R(deg1) ---
  {
    Col& c=t.col[1]; c.nslot=5; c.np=8;
    int ym[5][2]={{0,1},{1,0},{0,2},{1,1},{2,0}};
    for(int s=0;s<5;s++){ for(int q=0;q<6;q++)c.sexp[s][q]=0;
      c.sexp[s][1]=(int8_t)ym[s][0]; c.sexp[s][3]=(int8_t)ym[s][1]; }
    int p=0;
    for(int L=0;L<2;L++){
      c.pa[p]=(int8_t)L; c.pb[p]=4; c.gout[p]=(int16_t)slot;
      mslot[xidf(t,ym[L][0],ym[L][1])][xidf(t,2,0)]=slot; slot++; p++;
    }
    for(int i=0;i<3;i++)for(int j=0;j<2;j++){
      c.pa[p]=(int8_t)(2+i); c.pb[p]=(int8_t)j; c.gout[p]=(int16_t)slot;
      mslot[xidf(t,ym[2+i][0],ym[2+i][1])][xidf(t,ym[j][0],ym[j][1])]=slot; slot++; p++;
    }
  }
  // --- Cols 2/4: W1a/W2a = v(deg1) x {x2,x1,x2^2,x1x2} ---
  for(int wc=0; wc<2; wc++){
    Col& c=t.col[2+2*wc]; c.nslot=6; c.np=8;
    int am2[2][2]={{1,0},{0,1}};             // (v0e,v1e)
    int xb[4][2]={{0,1},{1,0},{0,2},{1,1}};  // (x1e,x2e)
    for(int s=0;s<6;s++) for(int q=0;q<6;q++) c.sexp[s][q]=0;
    for(int s=0;s<2;s++){
      c.sexp[s][wc?2:0]=(int8_t)am2[s][0]; c.sexp[s][wc?3:1]=(int8_t)am2[s][1];
    }
    for(int s=0;s<4;s++){ c.sexp[2+s][4]=(int8_t)xb[s][0]; c.sexp[2+s][5]=(int8_t)xb[s][1]; }
    int p=0;
    for(int a=0;a<2;a++)for(int b=0;b<4;b++){
      int amid = wc? aidf(t,0,0,am2[a][0],am2[a][1]) : aidf(t,am2[a][0],am2[a][1],0,0);
      if(amid<0) t.err+=1;
      c.pa[p]=(int8_t)a; c.pb[p]=(int8_t)(2+b); c.gout[p]=(int16_t)slot;
      wslot[amid][xidf(t,xb[b][0],xb[b][1])]=slot; slot++; p++;
    }
  }
  // --- Cols 3/5: W1b/W2b = v(deg1) x x1^2  +  v(deg2) x {x2,x1} ---
  for(int wc=0; wc<2; wc++){
    Col& c=t.col[3+2*wc]; c.nslot=8; c.np=8;
    int am5[5][2]={{1,0},{0,1},{2,0},{1,1},{0,2}};
    int xb[3][2]={{2,0},{0,1},{1,0}};        // slots 5,6,7
    for(int s=0;s<8;s++) for(int q=0;q<6;q++) c.sexp[s][q]=0;
    for(int s=0;s<5;s++){
      c.sexp[s][wc?2:0]=(int8_t)am5[s][0]; c.sexp[s][wc?3:1]=(int8_t)am5[s][1];
    }
    for(int s=0;s<3;s++){ c.sexp[5+s][4]=(int8_t)xb[s][0]; c.sexp[5+s][5]=(int8_t)xb[s][1]; }
    int p=0;
    for(int a=0;a<2;a++){
      int amid = wc? aidf(t,0,0,am5[a][0],am5[a][1]) : aidf(t,am5[a][0],am5[a][1],0,0);
      if(amid<0) t.err+=1;
      c.pa[p]=(int8_t)a; c.pb[p]=5; c.gout[p]=(int16_t)slot;
      wslot[amid][xidf(t,2,0)]=slot; slot++; p++;
    }
    for(int i=0;i<3;i++)for(int j=0;j<2;j++){
      int amid = wc? aidf(t,0,0,am5[2+i][0],am5[2+i][1]) : aidf(t,am5[2+i][0],am5[2+i][1],0,0);
      if(amid<0) t.err+=1;
      c.pa[p]=(int8_t)(2+i); c.pb[p]=(int8_t)(6+j); c.gout[p]=(int16_t)slot;
      wslot[amid][xidf(t,xb[1+j][0],xb[1+j][1])]=slot; slot++; p++;
    }
  }
  // --- Col 6: W3 = mixed-deg2 v x {x2,x1} ---
  {
    Col& c=t.col[6]; c.nslot=6; c.np=8;
    int a4[4][4]={{1,0,1,0},{1,0,0,1},{0,1,1,0},{0,1,0,1}};
    int xb[2][2]={{0,1},{1,0}};
    for(int s=0;s<6;s++) for(int q=0;q<6;q++) c.sexp[s][q]=0;
    for(int s=0;s<4;s++) for(int q=0;q<4;q++) c.sexp[s][q]=(int8_t)a4[s][q];
    for(int s=0;s<2;s++){ c.sexp[4+s][4]=(int8_t)xb[s][0]; c.sexp[4+s][5]=(int8_t)xb[s][1]; }
    int p=0;
    for(int a=0;a<4;a++)for(int b=0;b<2;b++){
      int amid = aidf(t,a4[a][0],a4[a][1],a4[a][2],a4[a][3]);
      if(amid<0) t.err+=1;
      c.pa[p]=(int8_t)a; c.pb[p]=(int8_t)(4+b); c.gout[p]=(int16_t)slot;
      wslot[amid][xidf(t,xb[b][0],xb[b][1])]=slot; slot++; p++;
    }
  }
  t.gcount=slot;
  if(slot!=NG) t.err+=1;

  // ldmask from slot exps
  for(int ci=0; ci<NCOLG; ci++){
    unsigned m=0;
    for(int s=0;s<t.col[ci].nslot;s++)
      for(int v=0;v<6;v++) if(t.col[ci].sexp[s][v]>0) m |= (1u<<v);
    t.col[ci].ldmask=(uint8_t)m;
  }

  // --- combine tables ---
  for(int i=0;i<t.nW;i++){
    const int8_t* e=t.expw[i];
    bool u0=(e[0]==0&&e[3]==0);
    bool v0=(e[1]==0&&e[2]==0&&e[4]==0&&e[5]==0);
    t.wpow[i]=e[6];
    if(u0){ t.wtype[i]=1; t.widx[i]=(int16_t)aidf(t,e[1],e[2],e[4],e[5]); }
    else if(v0){ t.wtype[i]=2; t.widx[i]=(int16_t)xidf(t,e[0],e[3]); }
    else {
      int s=wslot[aidf(t,e[1],e[2],e[4],e[5])][xidf(t,e[0],e[3])];
      if(s<0) t.err+=1;
      t.wtype[i]=0; t.widx[i]=(int16_t)s;
    }
  }
  for(int i=0;i<t.nM;i++){
    const int8_t* e=t.expm[i];
    bool L0=(e[1]==0&&e[3]==0), R0=(e[0]==0&&e[2]==0);
    t.mpow[i]=e[4];
    if(L0){ t.mtype[i]=2; t.midx[i]=(int16_t)aidf(t,0,e[0],0,e[2]); }
    else if(R0){ t.mtype[i]=1; t.midx[i]=(int16_t)aidf(t,0,e[1],0,e[3]); }
    else {
      int s=mslot[xidf(t,e[1],e[3])][xidf(t,e[0],e[2])];
      if(s<0) t.err+=1;
      t.mtype[i]=0; t.midx[i]=(int16_t)s;
    }
  }
  for(int i=0;i<t.nB;i++){
    const int8_t* e=t.expb[i];
    t.bcol[i]=(int16_t)aidf(t,0,e[0],0,e[1]); t.bpow[i]=e[2];
  }
  return t;
}

constexpr Tables TB = makeTables();
static_assert(TB.err==0 && TB.gcount==56, "table build failed");
static_assert(TB.nW==120 && TB.nB==20 && TB.nM==56 && TB.nA==35 && TB.nX==10, "enumeration mismatch");

// ---- helpers ----
template<int N, typename F>
DEV void sunroll(F&& f){
  if constexpr (N > 0){
    sunroll<N-1>(static_cast<F&&>(f));
    f(std::integral_constant<int, N-1>{});
  }
}
template<int E> DEV float ipw(float x){
  if constexpr(E==0) return 1.0f;
  else if constexpr(E==1) return x;
  else if constexpr(E==2) return x*x;
  else return x*x*x;
}
DEV u16 f2bf(float f){
  uint32_t u = __builtin_bit_cast(uint32_t, f);
  u = u + 0x7FFFu + ((u>>16)&1u);
  return (u16)(u>>16);
}

// Fragment-major LDS layout (r6-verified, conflict-free):
// element (b,ch) of a slot at u16 index ((b>>5)*4 + (ch>>4))*512
//   + (((b>>3)&3)*16 + (ch&15))*8 + (b&7)
DEV bf16x8 readFrag(const u16* L, int slot, int sb, int tt, int l){
  return *(const bf16x8*)&L[slot*4096 + ((sb*4 + tt)*64 + l)*8];
}
DEV f32x4 mfma_(bf16x8 a, bf16x8 b, f32x4 c){
  return __builtin_amdgcn_mfma_f32_16x16x32_bf16(a, b, c, 0, 0, 0);
}

// ---- GEMM column: 16 waves, nsplit=2 (each wave: 1 pair, 2 dd-tiles),
// ping-pong LDS, ONE barrier per chunk; MFMA || prefetch || stage co-issue ----
template<int CI>
DEV void colGemm(const float* __restrict__ s1,const float* __restrict__ y1,
                 const float* __restrict__ s2,const float* __restrict__ y2,
                 const float* __restrict__ x1,const float* __restrict__ x2,
                 float* __restrict__ G, u16* lds, int tid, int bi)
{
  constexpr int NS = TB.col[CI].nslot;
  constexpr unsigned LM = TB.col[CI].ldmask;

  const int l = tid&63, w = tid>>6;     // 16 waves
  // staging: thread (w,l) owns b = w*4+j (j=0..3), ch = l; u16x4 write.
  const int wbase = ((w>>3)*4 + (l>>4))*512 + (((w>>1)&3)*16 + (l&15))*8 + (w&1)*4;

  const int c0 = bi*CHW, c1 = c0+CHW;
  f32x4 acc[4][2] = {};
  float rw[6][4] = {};

  auto issue = [&](int ck){
    const int b0 = (ck*KB + w*4)*64 + l;
    #pragma unroll
    for(int j=0;j<4;j++){
      const int off = b0 + j*64;
      if constexpr(LM&1u)  rw[0][j]=s1[off];
      if constexpr(LM&2u)  rw[1][j]=y1[off];
      if constexpr(LM&4u)  rw[2][j]=s2[off];
      if constexpr(LM&8u)  rw[3][j]=y2[off];
      if constexpr(LM&16u) rw[4][j]=x1[off];
      if constexpr(LM&32u) rw[5][j]=x2[off];
    }
  };
  auto stage = [&](int buf){
    u16* L = lds + buf*BUFHALF;
    sunroll<NS>([&](auto S){
      constexpr int s = decltype(S)::value;
      u16x4 o4;
      #pragma unroll
      for(int j=0;j<4;j++){
        float v = ipw<TB.col[CI].sexp[s][0]>(rw[0][j])
                * ipw<TB.col[CI].sexp[s][1]>(rw[1][j])
                * ipw<TB.col[CI].sexp[s][2]>(rw[2][j])
                * ipw<TB.col[CI].sexp[s][3]>(rw[3][j])
                * ipw<TB.col[CI].sexp[s][4]>(rw[4][j])
                * ipw<TB.col[CI].sexp[s][5]>(rw[5][j]);
        o4[j]=f2bf(v);
      }
      *(u16x4*)&L[s*4096 + wbase] = o4;
    });
  };

  // prologue: load + stage chunk c0 into buffer 0
  issue(c0);
  stage(0);
  asm volatile("s_waitcnt lgkmcnt(0)" ::: "memory");
  __builtin_amdgcn_s_barrier();
  __builtin_amdgcn_sched_barrier(0);

  for(int k=c0; k<c1; ++k){
    const int t = k - c0;
    const bool notlast = (k+1 < c1);
    if(notlast) issue(k+1);             // global prefetch (latency under MFMA)

    // MFMA on buffer t&1
    const u16* L = lds + (t&1)*BUFHALF;
    sunroll<16>([&](auto WW){
      constexpr int ww = decltype(WW)::value;
      if(w==ww){
        constexpr int p  = ww>>1;
        constexpr int SA = TB.col[CI].pa[p];
        constexpr int SB = TB.col[CI].pb[p];
        constexpr int DB = (ww&1)*2;
        #pragma unroll
        for(int sb=0; sb<2; ++sb){
          bf16x8 Af[4];
          #pragma unroll
          for(int o2=0;o2<4;o2++) Af[o2]=readFrag(L,SA,sb,o2,l);
          #pragma unroll
          for(int dd=0;dd<2;dd++){
            bf16x8 Bf=readFrag(L,SB,sb,DB+dd,l);
            #pragma unroll
            for(int o2=0;o2<4;o2++) acc[o2][dd]=mfma_(Af[o2],Bf,acc[o2][dd]);
          }
        }
      }
    });

    if(notlast) stage((t+1)&1);         // stage next chunk into other buffer

    // one barrier per chunk: all LDS ops (reads+writes) drained, then sync
    asm volatile("s_waitcnt lgkmcnt(0)" ::: "memory");
    __builtin_amdgcn_s_barrier();
    __builtin_amdgcn_sched_barrier(0);
  }

  // epilogue: atomic partials (C/D layout: col=lane&15, row=(lane>>4)*4+reg)
  const int r0=(l>>4)*4, cc=l&15;
  sunroll<16>([&](auto WW){
    constexpr int ww = decltype(WW)::value;
    if(w==ww){
      constexpr int p  = ww>>1;
      constexpr int GS = TB.col[CI].gout[p];
      constexpr int DB = (ww&1)*2;
      float* dst = G + GS*4096;
      #pragma unroll
      for(int o2=0;o2<4;o2++)
        #pragma unroll
        for(int dd=0;dd<2;dd++)
          #pragma unroll
          for(int r=0;r<4;r++)
            atomicAdd(&dst[(o2*16+r0+r)*64 + (DB+dd)*16+cc], acc[o2][dd][r]);
    }
  });
}

// ---- colsum block (1024 thr): all 45 colsums over 2048 rows ----
DEV void colRed(const float* __restrict__ s1,const float* __restrict__ y1,
                const float* __restrict__ s2,const float* __restrict__ y2,
                const float* __restrict__ x1,const float* __restrict__ x2,
                float* __restrict__ col, float* ldsF, int tid, int bi)
{
  const int ch=tid&63, g16=tid>>6;
  const int base = bi*2048;
  float accv[45];
  sunroll<45>([&](auto K){ accv[decltype(K)::value]=0.f; });
  for(int r=base+g16; r<base+2048; r+=16){
    const int off=r*64+ch;
    const float v0=s1[off],v1=y1[off],v2=s2[off],v3=y2[off],v4=x1[off],v5=x2[off];
    sunroll<35>([&](auto K){
      constexpr int k=decltype(K)::value;
      accv[k] += ipw<TB.am[k][0]>(v0)*ipw<TB.am[k][1]>(v1)*ipw<TB.am[k][2]>(v2)*ipw<TB.am[k][3]>(v3);
    });
    sunroll<10>([&](auto K){
      constexpr int k=decltype(K)::value;
      accv[35+k] += ipw<TB.xm[k][0]>(v4)*ipw<TB.xm[k][1]>(v5);
    });
  }
  sunroll<6>([&](auto RR){
    constexpr int rr=decltype(RR)::value;
    __syncthreads();
    sunroll<8>([&](auto Q){
      constexpr int q=decltype(Q)::value;
      if constexpr(rr*8+q < 45)
        ldsF[(q*16+g16)*64+ch]=accv[rr*8+q];
    });
    __syncthreads();
    {
      const int k=tid>>6, c=tid&63;
      const int idx=rr*8+k;
      if(k<8 && idx<45){
        float s=0.f;
        #pragma unroll
        for(int gg=0; gg<16; gg++) s+=ldsF[(k*16+gg)*64+c];
        atomicAdd(&col[idx*64+c], s);
      }
    }
  });
}

__global__ __launch_bounds__(1024, 4) void k_main(
    const float* __restrict__ x1, const float* __restrict__ s1, const float* __restrict__ y1,
    const float* __restrict__ x2, const float* __restrict__ s2, const float* __restrict__ y2,
    float* __restrict__ G, float* __restrict__ col)
{
  __shared__ u16 lds[2*BUFHALF];   // 128 KiB -> 1 block/CU (by design)
  const int tid = threadIdx.x;
  const int u = blockIdx.x >> 5;   // unit
  const int g = blockIdx.x & 31;   // window (XCD = g%8)
  if      (u==0) colGemm<0>(s1,y1,s2,y2,x1,x2,G,lds,tid,g);
  else if (u==1) colGemm<1>(s1,y1,s2,y2,x1,x2,G,lds,tid,g);
  else if (u==2) colGemm<2>(s1,y1,s2,y2,x1,x2,G,lds,tid,g);
  else if (u==3) colGemm<3>(s1,y1,s2,y2,x1,x2,G,lds,tid,g);
  else if (u==4) colGemm<4>(s1,y1,s2,y2,x1,x2,G,lds,tid,g);
  else if (u==5) colGemm<5>(s1,y1,s2,y2,x1,x2,G,lds,tid,g);
  else if (u==6) colGemm<6>(s1,y1,s2,y2,x1,x2,G,lds,tid,g);
  else           colRed(s1,y1,s2,y2,x1,x2,col,(float*)lds,tid,g);
}

__global__ __launch_bounds__(256) void k_combine(
    const float* __restrict__ G, const float* __restrict__ col,
    const float* __restrict__ w, const float* __restrict__ b, const float* __restrict__ m,
    const float* __restrict__ parw, const float* __restrict__ parb, const float* __restrict__ parm,
    float* __restrict__ out)
{
  const int n = blockIdx.x*256 + threadIdx.x;   // 0..4095
  const int o = n>>6, d = n&63;
  const float wv = w[n], mv = m[n];
  const float wp[4] = {1.f, wv, wv*wv, wv*wv*wv};
  const float mp[4] = {1.f, mv, mv*mv, mv*mv*mv};
  float aw=0.f, am=0.f;
  sunroll<120>([&](auto II){
    constexpr int i = decltype(II)::value;
    constexpr int ty = TB.wtype[i];
    constexpr int ix = TB.widx[i];
    constexpr int q  = TB.wpow[i];
    float val;
    if constexpr(ty==0) val = G[ix*4096 + n];
    else if constexpr(ty==1) val = col[ix*64 + o];
    else val = col[(35+ix)*64 + d];
    aw += parw[i] * val * wp[q];
  });
  sunroll<56>([&](auto II){
    constexpr int i = decltype(II)::value;
    constexpr int ty = TB.mtype[i];
    constexpr int ix = TB.midx[i];
    constexpr int q  = TB.mpow[i];
    float val;
    if constexpr(ty==0) val = G[ix*4096 + n];
    else if constexpr(ty==1) val = col[ix*64 + o];
    else val = col[ix*64 + d];
    am += parm[i] * val * mp[q];
  });
  aw *= INVB; am *= INVB;
  if (o==d) am += parm[56];
  out[n] = aw;
  out[4160 + n] = am;
  if (n < 64){
    const float bv = b[n];
    const float bp[4] = {1.f, bv, bv*bv, bv*bv*bv};
    float ab=0.f;
    sunroll<20>([&](auto II){
      constexpr int i = decltype(II)::value;
      constexpr int cix = TB.bcol[i];
      constexpr int q = TB.bpow[i];
      ab += parb[i] * col[cix*64 + n] * bp[q];
    });
    out[4096 + n] = ab * INVB;
  }
}

extern "C" void kernel_launch(void* const* d_in, const int* in_sizes, int n_in,
                              void* d_out, int out_size, void* d_ws, size_t ws_size,
                              hipStream_t stream)
{
  const float* x1=(const float*)d_in[0];
  const float* s1=(const float*)d_in[1];
  const float* y1=(const float*)d_in[2];
  const float* x2=(const float*)d_in[3];
  const float* s2=(const float*)d_in[4];
  const float* y2=(const float*)d_in[5];
  const float* w =(const float*)d_in[6];
  const float* b =(const float*)d_in[7];
  const float* m =(const float*)d_in[8];
  const float* parw=(const float*)d_in[9];
  const float* parb=(const float*)d_in[10];
  const float* parm=(const float*)d_in[11];

  float* G   = (float*)d_ws;
  float* col = G + NG*4096;

  hipMemsetAsync(d_ws, 0, (size_t)(NG*4096 + NCOLSUM*64)*sizeof(float), stream);
  k_main<<<GRID, 1024, 0, stream>>>(x1,s1,y1,x2,s2,y2,G,col);
  k_combine<<<16, 256, 0, stream>>>(G,col,w,b,m,parw,parb,parm,(float*)d_out);
}